// Round 1
// baseline (2651.273 us; speedup 1.0000x reference)
//
#include <hip/hip_runtime.h>
#include <hip/hip_bf16.h>
#include <math.h>

// Problem constants
constexpr int Bc = 8;
constexpr int Sc = 1024;
constexpr int Dc = 768;
constexpr int Hc = 12;
constexpr int DKc = 64;
constexpr int BSc = Bc * Sc;          // 8192 rows
constexpr size_t HEAD_ELEMS = (size_t)Bc * Hc * Sc * DKc;  // 6291456
constexpr size_t OUT_ELEMS  = (size_t)Bc * Sc * Dc;        // 6291456

// ---------------------------------------------------------------------------
// Tiled fp32 GEMM: out = A[M,768] @ W[768,768] + bias
// MODE 0: scatter output into head-split [B,H,S,DK] layout (for Q/K/V ws)
// MODE 1: linear [M,768] output (for final projection)
// BM=BN=64, BK=16, 256 threads, 4x4 microtile per thread.
// ---------------------------------------------------------------------------
template <int MODE>
__global__ __launch_bounds__(256) void gemm_bias(
    const float* __restrict__ A, const float* __restrict__ W,
    const float* __restrict__ bias, float* __restrict__ out) {
  constexpr int BM = 64, BN = 64, BK = 16;
  constexpr int PAD = 68;  // 16B-aligned rows (68*4 = 272 = 16*17), conflict-free
  __shared__ float As[BK][PAD];  // As[kk][m]
  __shared__ float Bs[BK][PAD];  // Bs[kk][n]

  const int tid = threadIdx.x;
  const int row0 = blockIdx.x * BM;
  const int col0 = blockIdx.y * BN;
  const int tx = tid & 15;   // 0..15 -> 4 output cols tx*4..tx*4+3
  const int ty = tid >> 4;   // 0..15 -> 4 output rows ty*4..ty*4+3

  float acc[4][4] = {};

  for (int k0 = 0; k0 < Dc; k0 += BK) {
    // --- stage A tile (64 rows x 16 k), transposed into As[kk][m] ---
    {
      const int kk = tid & 15;        // 16 consecutive floats per row
      const int mbase = tid >> 4;     // 16 rows per pass
      #pragma unroll
      for (int i = 0; i < 4; i++) {
        const int m = mbase + i * 16;
        As[kk][m] = A[(size_t)(row0 + m) * Dc + k0 + kk];
      }
    }
    // --- stage B tile (16 k x 64 n) ---
    {
      const int c = tid & 63;
      const int kb = tid >> 6;        // 0..3
      #pragma unroll
      for (int i = 0; i < 4; i++) {
        const int kk = kb + i * 4;
        Bs[kk][c] = W[(size_t)(k0 + kk) * Dc + col0 + c];
      }
    }
    __syncthreads();

    #pragma unroll
    for (int kk = 0; kk < BK; kk++) {
      float a[4], b[4];
      #pragma unroll
      for (int i = 0; i < 4; i++) a[i] = As[kk][ty * 4 + i];
      #pragma unroll
      for (int j = 0; j < 4; j++) b[j] = Bs[kk][tx * 4 + j];
      #pragma unroll
      for (int i = 0; i < 4; i++)
        #pragma unroll
        for (int j = 0; j < 4; j++) acc[i][j] += a[i] * b[j];
    }
    __syncthreads();
  }

  // --- epilogue: bias + store (float4 per row) ---
  #pragma unroll
  for (int i = 0; i < 4; i++) {
    const int r = row0 + ty * 4 + i;
    const int c0 = col0 + tx * 4;
    float4 v;
    v.x = acc[i][0] + bias[c0 + 0];
    v.y = acc[i][1] + bias[c0 + 1];
    v.z = acc[i][2] + bias[c0 + 2];
    v.w = acc[i][3] + bias[c0 + 3];
    if (MODE == 0) {
      const int b_ = r >> 10, s_ = r & 1023;
      const int h_ = c0 >> 6, dk = c0 & 63;
      float* p = out + (((size_t)(b_ * Hc + h_)) * Sc + s_) * DKc + dk;
      *reinterpret_cast<float4*>(p) = v;
    } else {
      float* p = out + (size_t)r * Dc + c0;
      *reinterpret_cast<float4*>(p) = v;
    }
  }
}

// ---------------------------------------------------------------------------
// Flash attention, fp32. One thread = one q row (q + acc in registers).
// Block = 256 threads = 256 q rows; grid = B*H*(S/256) = 384 blocks.
// K/V staged in LDS 64 rows at a time; all lanes read same LDS address
// (broadcast, conflict-free). Online softmax per 16-k subtile.
// ---------------------------------------------------------------------------
__global__ __launch_bounds__(256) void attn_flash(
    const float* __restrict__ Q, const float* __restrict__ K,
    const float* __restrict__ V, float* __restrict__ ctx_out) {
  constexpr int KT = 64;   // k rows per LDS tile
  constexpr int PAD = 68;  // 16B-aligned rows
  __shared__ float Ks[KT][PAD];
  __shared__ float Vs[KT][PAD];

  const int tid = threadIdx.x;
  const int blk = blockIdx.x;      // (b*H+h)*4 + qt
  const int bh = blk >> 2;
  const int qt = blk & 3;
  const int qrow = qt * 256 + tid;

  // load q row into registers, pre-scaled by 1/sqrt(DK) = 1/8
  const float* qptr = Q + ((size_t)bh * Sc + qrow) * DKc;
  float q[DKc];
  #pragma unroll
  for (int d = 0; d < DKc; d += 4) {
    float4 t = *reinterpret_cast<const float4*>(qptr + d);
    q[d + 0] = t.x * 0.125f;
    q[d + 1] = t.y * 0.125f;
    q[d + 2] = t.z * 0.125f;
    q[d + 3] = t.w * 0.125f;
  }

  float acc[DKc];
  #pragma unroll
  for (int d = 0; d < DKc; d++) acc[d] = 0.f;
  float m = -1e30f, l = 0.f;

  const float* kbase = K + (size_t)bh * Sc * DKc;
  const float* vbase = V + (size_t)bh * Sc * DKc;

  for (int kt = 0; kt < Sc; kt += KT) {
    __syncthreads();  // protect previous tile's consumers
    #pragma unroll
    for (int i = 0; i < 16; i++) {
      const int idx = i * 256 + tid;
      const int r = idx >> 6, c = idx & 63;
      Ks[r][c] = kbase[(size_t)(kt + r) * DKc + c];
      Vs[r][c] = vbase[(size_t)(kt + r) * DKc + c];
    }
    __syncthreads();

    #pragma unroll 1
    for (int ks = 0; ks < KT; ks += 16) {
      float s[16];
      #pragma unroll
      for (int i = 0; i < 16; i++) {
        float a0 = 0.f;
        #pragma unroll
        for (int d = 0; d < DKc; d++) a0 += q[d] * Ks[ks + i][d];
        s[i] = a0;
      }
      float tmax = s[0];
      #pragma unroll
      for (int i = 1; i < 16; i++) tmax = fmaxf(tmax, s[i]);
      const float m_new = fmaxf(m, tmax);
      const float scale = __expf(m - m_new);
      m = m_new;
      l *= scale;
      #pragma unroll
      for (int d = 0; d < DKc; d++) acc[d] *= scale;
      #pragma unroll
      for (int i = 0; i < 16; i++) {
        const float w = __expf(s[i] - m_new);
        l += w;
        #pragma unroll
        for (int d = 0; d < DKc; d++) acc[d] += w * Vs[ks + i][d];
      }
    }
  }

  const float inv = 1.f / l;
  const int b_ = bh / Hc, h_ = bh % Hc;
  float* op = ctx_out + ((size_t)(b_ * Sc + qrow)) * Dc + h_ * DKc;
  #pragma unroll
  for (int d = 0; d < DKc; d += 4) {
    float4 t;
    t.x = acc[d + 0] * inv;
    t.y = acc[d + 1] * inv;
    t.z = acc[d + 2] * inv;
    t.w = acc[d + 3] * inv;
    *reinterpret_cast<float4*>(op + d) = t;
  }
}

// ---------------------------------------------------------------------------
extern "C" void kernel_launch(void* const* d_in, const int* in_sizes, int n_in,
                              void* d_out, int out_size, void* d_ws,
                              size_t ws_size, hipStream_t stream) {
  const float* query = (const float*)d_in[0];
  const float* key_  = (const float*)d_in[1];
  const float* value = (const float*)d_in[2];
  const float* Wq = (const float*)d_in[3];
  const float* bq = (const float*)d_in[4];
  const float* Wk = (const float*)d_in[5];
  const float* bk = (const float*)d_in[6];
  const float* Wv = (const float*)d_in[7];
  const float* bv = (const float*)d_in[8];
  const float* Wd = (const float*)d_in[9];
  const float* bd = (const float*)d_in[10];

  float* out = (float*)d_out;
  float* hidden = out;                 // [B,S,D]
  float* context = out + OUT_ELEMS;    // [B,S,D]

  float* ws = (float*)d_ws;
  float* Qw = ws;                       // [B,H,S,DK]
  float* Kw = Qw + HEAD_ELEMS;
  float* Vw = Kw + HEAD_ELEMS;

  const dim3 ggrid(BSc / 64, Dc / 64);  // 128 x 12
  // QKV projections -> head-split layout in ws
  gemm_bias<0><<<ggrid, 256, 0, stream>>>(query, Wq, bq, Qw);
  gemm_bias<0><<<ggrid, 256, 0, stream>>>(key_, Wk, bk, Kw);
  gemm_bias<0><<<ggrid, 256, 0, stream>>>(value, Wv, bv, Vw);

  // attention -> context (second output)
  attn_flash<<<Bc * Hc * (Sc / 256), 256, 0, stream>>>(Qw, Kw, Vw, context);

  // output projection: hidden = context @ Wd + bd
  gemm_bias<1><<<ggrid, 256, 0, stream>>>(context, Wd, bd, hidden);
}

// Round 4
// 716.726 us; speedup vs baseline: 3.6991x; 3.6991x over previous
//
#include <hip/hip_runtime.h>
#include <hip/hip_bf16.h>
#include <math.h>

// Problem constants
constexpr int Bc = 8;
constexpr int Sc = 1024;
constexpr int Dc = 768;
constexpr int Hc = 12;
constexpr int DKc = 64;
constexpr int BSc = Bc * Sc;          // 8192 rows
constexpr size_t HEAD_ELEMS = (size_t)Bc * Hc * Sc * DKc;  // 6291456
constexpr size_t OUT_ELEMS  = (size_t)Bc * Sc * Dc;        // 6291456

typedef __attribute__((ext_vector_type(8))) short short8;
typedef __attribute__((ext_vector_type(4))) short short4v;
typedef __attribute__((ext_vector_type(4))) float f32x4;

__device__ __forceinline__ short f2bf(float x) {
  __hip_bfloat16 h = __float2bfloat16(x);
  short r;
  __builtin_memcpy(&r, &h, 2);
  return r;
}

// ---------------------------------------------------------------------------
// Tiled fp32 GEMM: out = A[M,768] @ W[768,768] + bias
// MODE 0: bf16 head-split [B,H,S,DK]   (Q, K)
// MODE 1: fp32 linear [M,768]          (final projection)
// MODE 2: bf16 transposed head-split [B,H,DK,S]   (V)
// ---------------------------------------------------------------------------
template <int MODE>
__global__ __launch_bounds__(256) void gemm_bias(
    const float* __restrict__ A, const float* __restrict__ W,
    const float* __restrict__ bias, void* __restrict__ out) {
  constexpr int BM = 64, BN = 64, BK = 16;
  constexpr int PAD = 68;
  __shared__ float As[BK][PAD];  // As[kk][m]
  __shared__ float Bs[BK][PAD];  // Bs[kk][n]

  const int tid = threadIdx.x;
  const int row0 = blockIdx.x * BM;
  const int col0 = blockIdx.y * BN;
  const int tx = tid & 15;
  const int ty = tid >> 4;

  float acc[4][4] = {};

  for (int k0 = 0; k0 < Dc; k0 += BK) {
    {
      const int kk = tid & 15;
      const int mbase = tid >> 4;
      #pragma unroll
      for (int i = 0; i < 4; i++) {
        const int m = mbase + i * 16;
        As[kk][m] = A[(size_t)(row0 + m) * Dc + k0 + kk];
      }
    }
    {
      const int c = tid & 63;
      const int kb = tid >> 6;
      #pragma unroll
      for (int i = 0; i < 4; i++) {
        const int kk = kb + i * 4;
        Bs[kk][c] = W[(size_t)(k0 + kk) * Dc + col0 + c];
      }
    }
    __syncthreads();

    #pragma unroll
    for (int kk = 0; kk < BK; kk++) {
      float a[4], b[4];
      #pragma unroll
      for (int i = 0; i < 4; i++) a[i] = As[kk][ty * 4 + i];
      #pragma unroll
      for (int j = 0; j < 4; j++) b[j] = Bs[kk][tx * 4 + j];
      #pragma unroll
      for (int i = 0; i < 4; i++)
        #pragma unroll
        for (int j = 0; j < 4; j++) acc[i][j] += a[i] * b[j];
    }
    __syncthreads();
  }

  if constexpr (MODE == 2) {
    // transposed head-split store: Vt[b][h][dk][s], short4 along s
    const int r0 = row0 + ty * 4;          // 4 consecutive rows (= s)
    const int b_ = r0 >> 10, s0 = r0 & 1023;
    #pragma unroll
    for (int j = 0; j < 4; j++) {
      const int c = col0 + tx * 4 + j;     // d index
      const int h_ = c >> 6, dk = c & 63;
      const float bj = bias[c];
      short4v sv;
      sv[0] = f2bf(acc[0][j] + bj);
      sv[1] = f2bf(acc[1][j] + bj);
      sv[2] = f2bf(acc[2][j] + bj);
      sv[3] = f2bf(acc[3][j] + bj);
      __hip_bfloat16* p = (__hip_bfloat16*)out +
          (((size_t)(b_ * Hc + h_)) * DKc + dk) * Sc + s0;
      *reinterpret_cast<short4v*>(p) = sv;
    }
  } else {
    #pragma unroll
    for (int i = 0; i < 4; i++) {
      const int r = row0 + ty * 4 + i;
      const int c0 = col0 + tx * 4;
      float v0 = acc[i][0] + bias[c0 + 0];
      float v1 = acc[i][1] + bias[c0 + 1];
      float v2 = acc[i][2] + bias[c0 + 2];
      float v3 = acc[i][3] + bias[c0 + 3];
      if constexpr (MODE == 0) {
        const int b_ = r >> 10, s_ = r & 1023;
        const int h_ = c0 >> 6, dk = c0 & 63;
        __hip_bfloat16* p = (__hip_bfloat16*)out +
            (((size_t)(b_ * Hc + h_)) * Sc + s_) * DKc + dk;
        short4v sv;
        sv[0] = f2bf(v0); sv[1] = f2bf(v1); sv[2] = f2bf(v2); sv[3] = f2bf(v3);
        *reinterpret_cast<short4v*>(p) = sv;
      } else {
        float4 v; v.x = v0; v.y = v1; v.z = v2; v.w = v3;
        float* p = (float*)out + (size_t)r * Dc + c0;
        *reinterpret_cast<float4*>(p) = v;
      }
    }
  }
}

// ---------------------------------------------------------------------------
// BF16 MFMA flash attention (no inline asm, no tr_read).
// Grid: B*H*(S/64) = 1536 blocks of 256 threads (4 waves, 16 q-rows each).
// K tile LDS [kv=64][d=64], V tile LDS [d=64][kv=64] (from global Vt),
// both with 16B-chunk XOR swizzle: byte = row*128 + 16*(chunk ^ (row&7)).
// Swapped QK^T: sacc = mfma(K_frag, Q_frag) -> C/D col(lane&15)=q,
// row((lane>>4)*4+reg)=kv-within-16  [m89-verified C/D map].
// PV: pa (P->bf16, k-map kv=32c+16hi+4g+j) x vf (2x ds_read_b64 from Vs,
// same k-map) -> invariance cancels the unverified within-lane k order.
// ---------------------------------------------------------------------------
__global__ __launch_bounds__(256) void attn_mfma(
    const __hip_bfloat16* __restrict__ Q, const __hip_bfloat16* __restrict__ K,
    const __hip_bfloat16* __restrict__ Vt, float* __restrict__ ctx) {
  __shared__ __hip_bfloat16 Ks[64 * 64];   // 8 KB
  __shared__ __hip_bfloat16 Vs[64 * 64];   // 8 KB, transposed tile [d][kv]

  const int tid = threadIdx.x;
  const int lane = tid & 63;
  const int w = tid >> 6;
  const int l15 = lane & 15;
  const int g = lane >> 4;

  // XCD-aware swizzle (nwg=1536, divisible by 8 -> bijective)
  const int cpx = gridDim.x >> 3;
  const int bid = blockIdx.x;
  const int wid = (bid & 7) * cpx + (bid >> 3);
  const int bh = wid >> 4;       // (b*H + h)
  const int qt = wid & 15;
  const int qbase = qt * 64 + w * 16;

  const __hip_bfloat16* Qb = Q + (size_t)bh * Sc * DKc;
  const __hip_bfloat16* Kb = K + (size_t)bh * Sc * DKc;
  const __hip_bfloat16* Vtb = Vt + (size_t)bh * DKc * Sc;  // [64][1024]

  // hoisted Q fragments (B-operand): qf[c][i] = Q[qbase+l15][g*8 + i + 32*c]
  short8 qf[2];
  {
    const __hip_bfloat16* qp = Qb + (size_t)(qbase + l15) * DKc + g * 8;
    qf[0] = *reinterpret_cast<const short8*>(qp);
    qf[1] = *reinterpret_cast<const short8*>(qp + 32);
  }

  f32x4 Oacc[4];
  #pragma unroll
  for (int dt = 0; dt < 4; dt++) Oacc[dt] = f32x4{0.f, 0.f, 0.f, 0.f};
  float m_run = -1e30f, l_run = 0.f;

  // softmax scale folded into exp2: (1/8) * log2(e)
  constexpr float SM_SCALE = 0.125f * 1.44269504088896340736f;

  for (int kt = 0; kt < Sc; kt += 64) {
    __syncthreads();
    // ---- stage K and Vt tiles, both XOR-swizzled ----
    #pragma unroll
    for (int it = 0; it < 2; it++) {
      const int tt = tid + it * 256;      // 512 chunks each of 16B
      const int row = tt >> 3, s = tt & 7;
      const float4 kv = *reinterpret_cast<const float4*>(
          Kb + (size_t)(kt + row) * DKc + s * 8);
      const float4 vv = *reinterpret_cast<const float4*>(
          Vtb + (size_t)row * Sc + kt + s * 8);
      const int off = row * 128 + ((s ^ (row & 7)) << 4);
      *reinterpret_cast<float4*>((char*)Ks + off) = kv;
      *reinterpret_cast<float4*>((char*)Vs + off) = vv;
    }
    __syncthreads();

    // ---- QK^T (swapped): sacc[mt] = K-rows x Q^T ----
    f32x4 sacc[4];
    #pragma unroll
    for (int mt = 0; mt < 4; mt++) sacc[mt] = f32x4{0.f, 0.f, 0.f, 0.f};
    #pragma unroll
    for (int c = 0; c < 2; c++) {
      #pragma unroll
      for (int mt = 0; mt < 4; mt++) {
        const int row = mt * 16 + l15;
        const short8 kf = *reinterpret_cast<const short8*>(
            (char*)Ks + row * 128 + (((g + 4 * c) ^ (row & 7)) << 4));
        sacc[mt] =
            __builtin_amdgcn_mfma_f32_16x16x32_bf16(kf, qf[c], sacc[mt], 0, 0, 0);
      }
    }

    // ---- online softmax; lane holds scores for q=l15 at kv = s*16+g*4+r
    float tmax = -1e30f;
    #pragma unroll
    for (int s = 0; s < 4; s++)
      #pragma unroll
      for (int r = 0; r < 4; r++) tmax = fmaxf(tmax, sacc[s][r]);
    tmax = fmaxf(tmax, __shfl_xor(tmax, 16));
    tmax = fmaxf(tmax, __shfl_xor(tmax, 32));
    const float mnew = fmaxf(m_run, tmax);
    const float alpha = __builtin_amdgcn_exp2f((m_run - mnew) * SM_SCALE);
    m_run = mnew;
    float wgt[4][4];
    float wsum = 0.f;
    #pragma unroll
    for (int s = 0; s < 4; s++)
      #pragma unroll
      for (int r = 0; r < 4; r++) {
        wgt[s][r] = __builtin_amdgcn_exp2f((sacc[s][r] - mnew) * SM_SCALE);
        wsum += wgt[s][r];
      }
    l_run = l_run * alpha + wsum;

    // rescale O: O rows are q' = g*4 + r; alpha for q' lives at lane q'
    float ar[4];
    #pragma unroll
    for (int r = 0; r < 4; r++) ar[r] = __shfl(alpha, g * 4 + r);
    #pragma unroll
    for (int dt = 0; dt < 4; dt++)
      #pragma unroll
      for (int r = 0; r < 4; r++) Oacc[dt][r] *= ar[r];

    // P -> bf16 A-frags: pa[c][hi*4+j] <-> kv = 32c + 16hi + 4g + j
    short8 pa[2];
    #pragma unroll
    for (int c = 0; c < 2; c++)
      #pragma unroll
      for (int i = 0; i < 8; i++) pa[c][i] = f2bf(wgt[2 * c + (i >> 2)][i & 3]);

    // ---- PV: vf via 2x ds_read_b64 from transposed V tile, same k-map ----
    #pragma unroll
    for (int dt = 0; dt < 4; dt++) {
      const int row = dt * 16 + l15;
      const int rb = row * 128;
      const int sw = row & 7;            // == l15 & 7
      const int gl = (g & 1) * 8;
      const int gh = g >> 1;
      #pragma unroll
      for (int c = 0; c < 2; c++) {
        const short4v v0 = *reinterpret_cast<const short4v*>(
            (char*)Vs + rb + ((((4 * c + 0) + gh) ^ sw) << 4) + gl);
        const short4v v1 = *reinterpret_cast<const short4v*>(
            (char*)Vs + rb + ((((4 * c + 2) + gh) ^ sw) << 4) + gl);
        const short8 vf =
            __builtin_shufflevector(v0, v1, 0, 1, 2, 3, 4, 5, 6, 7);
        Oacc[dt] =
            __builtin_amdgcn_mfma_f32_16x16x32_bf16(pa[c], vf, Oacc[dt], 0, 0, 0);
      }
    }
  }

  // ---- finalize: reduce l across the 4 lanes sharing q, divide, store ----
  l_run += __shfl_xor(l_run, 16);
  l_run += __shfl_xor(l_run, 32);
  float linv[4];
  #pragma unroll
  for (int r = 0; r < 4; r++) linv[r] = 1.0f / __shfl(l_run, g * 4 + r);

  const int b_ = bh / Hc, h_ = bh % Hc;
  #pragma unroll
  for (int dt = 0; dt < 4; dt++)
    #pragma unroll
    for (int r = 0; r < 4; r++) {
      const int qa = qbase + g * 4 + r;
      float* p = ctx + ((size_t)(b_ * Sc + qa)) * Dc + h_ * 64 + dt * 16 + l15;
      *p = Oacc[dt][r] * linv[r];
    }
}

// ---------------------------------------------------------------------------
extern "C" void kernel_launch(void* const* d_in, const int* in_sizes, int n_in,
                              void* d_out, int out_size, void* d_ws,
                              size_t ws_size, hipStream_t stream) {
  const float* query = (const float*)d_in[0];
  const float* key_  = (const float*)d_in[1];
  const float* value = (const float*)d_in[2];
  const float* Wq = (const float*)d_in[3];
  const float* bq = (const float*)d_in[4];
  const float* Wk = (const float*)d_in[5];
  const float* bk = (const float*)d_in[6];
  const float* Wv = (const float*)d_in[7];
  const float* bv = (const float*)d_in[8];
  const float* Wd = (const float*)d_in[9];
  const float* bd = (const float*)d_in[10];

  float* out = (float*)d_out;
  float* hidden = out;                 // [B,S,D]
  float* context = out + OUT_ELEMS;    // [B,S,D]

  __hip_bfloat16* Qw = (__hip_bfloat16*)d_ws;        // [B,H,S,DK] bf16
  __hip_bfloat16* Kw = Qw + HEAD_ELEMS;
  __hip_bfloat16* Vtw = Kw + HEAD_ELEMS;             // [B,H,DK,S] bf16

  const dim3 ggrid(BSc / 64, Dc / 64);  // 128 x 12
  gemm_bias<0><<<ggrid, 256, 0, stream>>>(query, Wq, bq, Qw);
  gemm_bias<0><<<ggrid, 256, 0, stream>>>(key_, Wk, bk, Kw);
  gemm_bias<2><<<ggrid, 256, 0, stream>>>(value, Wv, bv, Vtw);

  attn_mfma<<<Bc * Hc * (Sc / 64), 256, 0, stream>>>(Qw, Kw, Vtw, context);

  gemm_bias<1><<<ggrid, 256, 0, stream>>>(context, Wd, bd, hidden);
}

// Round 8
// 300.679 us; speedup vs baseline: 8.8176x; 2.3837x over previous
//
#include <hip/hip_runtime.h>
#include <hip/hip_bf16.h>
#include <math.h>

// Problem constants
constexpr int Bc = 8;
constexpr int Sc = 1024;
constexpr int Dc = 768;
constexpr int Hc = 12;
constexpr int DKc = 64;
constexpr int BSc = Bc * Sc;          // 8192 rows
constexpr size_t HEAD_ELEMS = (size_t)Bc * Hc * Sc * DKc;  // 6291456
constexpr size_t OUT_ELEMS  = (size_t)Bc * Sc * Dc;        // 6291456

typedef __attribute__((ext_vector_type(8))) short short8;
typedef __attribute__((ext_vector_type(4))) short short4v;
typedef __attribute__((ext_vector_type(4))) float f32x4;

__device__ __forceinline__ short f2bf(float x) {
  __hip_bfloat16 h = __float2bfloat16(x);
  short r;
  __builtin_memcpy(&r, &h, 2);
  return r;
}

// async global->LDS, 16B per lane. LDS dest = wave-uniform base + lane*16.
__device__ __forceinline__ void gload16(const void* g, void* l) {
  __builtin_amdgcn_global_load_lds(
      (const __attribute__((address_space(1))) void*)g,
      (__attribute__((address_space(3))) void*)l, 16, 0, 0);
}

// ---------------------------------------------------------------------------
// Weight transpose+cast: Wt[n][k] bf16 = W[k][n] fp32.  Grid (24,24), 256 thr.
// ---------------------------------------------------------------------------
__global__ __launch_bounds__(256) void wtrans(
    const float* __restrict__ W, __hip_bfloat16* __restrict__ Wt) {
  __shared__ float t[32][33];
  const int tx = threadIdx.x & 31, ty = threadIdx.x >> 5;
  const int bx = blockIdx.x * 32;   // n-base
  const int by = blockIdx.y * 32;   // k-base
  #pragma unroll
  for (int i = 0; i < 32; i += 8)
    t[ty + i][tx] = W[(size_t)(by + ty + i) * Dc + bx + tx];
  __syncthreads();
  #pragma unroll
  for (int i = 0; i < 32; i += 8)
    Wt[(size_t)(bx + ty + i) * Dc + by + tx] = __float2bfloat16(t[tx][ty + i]);
}

// ---------------------------------------------------------------------------
// BF16 MFMA GEMM: C[M=8192, N=768] = A[M,768](fp32) @ Wt[N,768](bf16)^T + bias
// m97 structure: 128x128 tile, BK=64, 4 waves (2x2), 64x64 per wave,
// 2-barrier K-loop. B-tile staged via global_load_lds (linear LDS);
// A-tile reg-staged fp32->bf16 (fuses the cast).
// MODE 0: bf16 head-split [B,H,S,DK]     (Q, K)
// MODE 1: fp32 linear [M,768]            (hidden)
// MODE 2: bf16 transposed [B,H,DK,S]     (V) -- via swapped MFMA operands
// ---------------------------------------------------------------------------
template <int MODE>
__global__ __launch_bounds__(256) void gemm_mfma(
    const float* __restrict__ A, const __hip_bfloat16* __restrict__ Wt,
    const float* __restrict__ bias, void* __restrict__ out) {
  __shared__ __hip_bfloat16 As[128 * 64];   // 16 KB, [m][k] linear
  __shared__ __hip_bfloat16 Bs[128 * 64];   // 16 KB, [n][k] linear

  const int tid = threadIdx.x;
  const int lane = tid & 63;
  const int wv = tid >> 6;
  const int l15 = lane & 15;
  const int g = lane >> 4;
  const int wr = wv >> 1, wc = wv & 1;

  // XCD-aware swizzle; nwg = 384, divisible by 8 -> bijective
  const int nwg = gridDim.x;
  const int orig = blockIdx.x;
  const int swz = (orig & 7) * (nwg >> 3) + (orig >> 3);
  const int rb = swz / (Dc / 128);
  const int cb = swz % (Dc / 128);
  const int row0 = rb * 128, col0 = cb * 128;

  f32x4 acc[4][4];
  #pragma unroll
  for (int ai = 0; ai < 4; ai++)
    #pragma unroll
    for (int bj = 0; bj < 4; bj++) acc[ai][bj] = f32x4{0.f, 0.f, 0.f, 0.f};

  for (int k0 = 0; k0 < Dc; k0 += 64) {
    __syncthreads();   // protect LDS from previous iteration's readers

    // ---- B tile: 4 async calls/wave; rows j*32 + wv*8 + (lane>>3) ----
    #pragma unroll
    for (int j = 0; j < 4; j++) {
      const int r = j * 32 + wv * 8 + (lane >> 3);
      const __hip_bfloat16* gp =
          Wt + (size_t)(col0 + r) * Dc + k0 + (lane & 7) * 8;
      gload16(gp, &Bs[(j * 32 + wv * 8) * 64]);
    }

    // ---- A tile: reg-staged fp32 -> bf16 ----
    #pragma unroll
    for (int i = 0; i < 4; i++) {
      const int id = tid + i * 256;          // 1024 chunks of 8 elems
      const int r = id >> 3, gi = id & 7;
      const float* ap = A + (size_t)(row0 + r) * Dc + k0 + gi * 8;
      const float4 f0 = *reinterpret_cast<const float4*>(ap);
      const float4 f1 = *reinterpret_cast<const float4*>(ap + 4);
      short8 s;
      s[0] = f2bf(f0.x); s[1] = f2bf(f0.y); s[2] = f2bf(f0.z); s[3] = f2bf(f0.w);
      s[4] = f2bf(f1.x); s[5] = f2bf(f1.y); s[6] = f2bf(f1.z); s[7] = f2bf(f1.w);
      *reinterpret_cast<short8*>(&As[r * 64 + gi * 8]) = s;
    }
    __syncthreads();   // drains vmcnt (gload_lds) + lgkm (ds_write)

    // ---- compute: 2 k-chunks of 32, 16 MFMA each per wave ----
    #pragma unroll
    for (int kk = 0; kk < 2; kk++) {
      short8 a[4], b[4];
      #pragma unroll
      for (int ai = 0; ai < 4; ai++)
        a[ai] = *reinterpret_cast<const short8*>(
            &As[(wr * 64 + ai * 16 + l15) * 64 + kk * 32 + g * 8]);
      #pragma unroll
      for (int bj = 0; bj < 4; bj++)
        b[bj] = *reinterpret_cast<const short8*>(
            &Bs[(wc * 64 + bj * 16 + l15) * 64 + kk * 32 + g * 8]);
      #pragma unroll
      for (int ai = 0; ai < 4; ai++)
        #pragma unroll
        for (int bj = 0; bj < 4; bj++) {
          if constexpr (MODE == 2)
            acc[ai][bj] = __builtin_amdgcn_mfma_f32_16x16x32_bf16(
                b[bj], a[ai], acc[ai][bj], 0, 0, 0);
          else
            acc[ai][bj] = __builtin_amdgcn_mfma_f32_16x16x32_bf16(
                a[ai], b[bj], acc[ai][bj], 0, 0, 0);
        }
    }
  }

  // ---- epilogue: bias + store.  C/D map: col=lane&15, row=g*4+reg ----
  const int mb = row0 + wr * 64, nb = col0 + wc * 64;
  #pragma unroll
  for (int ai = 0; ai < 4; ai++)
    #pragma unroll
    for (int bj = 0; bj < 4; bj++)
      #pragma unroll
      for (int reg = 0; reg < 4; reg++) {
        const float v = acc[ai][bj][reg];
        if constexpr (MODE == 2) {
          // swapped operands: D row = n(dk-side), D col = m(s-side)
          const int n = nb + bj * 16 + g * 4 + reg;
          const int m = mb + ai * 16 + l15;
          const float val = v + bias[n];
          const int b_ = m >> 10, s_ = m & 1023;
          const int h_ = n >> 6, dk = n & 63;
          ((__hip_bfloat16*)out)[(((size_t)(b_ * Hc + h_)) * DKc + dk) * Sc + s_] =
              __float2bfloat16(val);
        } else {
          const int m = mb + ai * 16 + g * 4 + reg;
          const int n = nb + bj * 16 + l15;
          const float val = v + bias[n];
          if constexpr (MODE == 0) {
            const int b_ = m >> 10, s_ = m & 1023;
            const int h_ = n >> 6, dk = n & 63;
            ((__hip_bfloat16*)out)[(((size_t)(b_ * Hc + h_)) * Sc + s_) * DKc + dk] =
                __float2bfloat16(val);
          } else {
            ((float*)out)[(size_t)m * Dc + n] = val;
          }
        }
      }
}

// ---------------------------------------------------------------------------
// BF16 MFMA flash attention (unchanged -- verified round 4).
// ---------------------------------------------------------------------------
__global__ __launch_bounds__(256) void attn_mfma(
    const __hip_bfloat16* __restrict__ Q, const __hip_bfloat16* __restrict__ K,
    const __hip_bfloat16* __restrict__ Vt, float* __restrict__ ctx) {
  __shared__ __hip_bfloat16 Ks[64 * 64];   // 8 KB
  __shared__ __hip_bfloat16 Vs[64 * 64];   // 8 KB, transposed tile [d][kv]

  const int tid = threadIdx.x;
  const int lane = tid & 63;
  const int w = tid >> 6;
  const int l15 = lane & 15;
  const int g = lane >> 4;

  const int cpx = gridDim.x >> 3;
  const int bid = blockIdx.x;
  const int wid = (bid & 7) * cpx + (bid >> 3);
  const int bh = wid >> 4;       // (b*H + h)
  const int qt = wid & 15;
  const int qbase = qt * 64 + w * 16;

  const __hip_bfloat16* Qb = Q + (size_t)bh * Sc * DKc;
  const __hip_bfloat16* Kb = K + (size_t)bh * Sc * DKc;
  const __hip_bfloat16* Vtb = Vt + (size_t)bh * DKc * Sc;  // [64][1024]

  short8 qf[2];
  {
    const __hip_bfloat16* qp = Qb + (size_t)(qbase + l15) * DKc + g * 8;
    qf[0] = *reinterpret_cast<const short8*>(qp);
    qf[1] = *reinterpret_cast<const short8*>(qp + 32);
  }

  f32x4 Oacc[4];
  #pragma unroll
  for (int dt = 0; dt < 4; dt++) Oacc[dt] = f32x4{0.f, 0.f, 0.f, 0.f};
  float m_run = -1e30f, l_run = 0.f;

  constexpr float SM_SCALE = 0.125f * 1.44269504088896340736f;

  for (int kt = 0; kt < Sc; kt += 64) {
    __syncthreads();
    #pragma unroll
    for (int it = 0; it < 2; it++) {
      const int tt = tid + it * 256;
      const int row = tt >> 3, s = tt & 7;
      const float4 kv = *reinterpret_cast<const float4*>(
          Kb + (size_t)(kt + row) * DKc + s * 8);
      const float4 vv = *reinterpret_cast<const float4*>(
          Vtb + (size_t)row * Sc + kt + s * 8);
      const int off = row * 128 + ((s ^ (row & 7)) << 4);
      *reinterpret_cast<float4*>((char*)Ks + off) = kv;
      *reinterpret_cast<float4*>((char*)Vs + off) = vv;
    }
    __syncthreads();

    f32x4 sacc[4];
    #pragma unroll
    for (int mt = 0; mt < 4; mt++) sacc[mt] = f32x4{0.f, 0.f, 0.f, 0.f};
    #pragma unroll
    for (int c = 0; c < 2; c++) {
      #pragma unroll
      for (int mt = 0; mt < 4; mt++) {
        const int row = mt * 16 + l15;
        const short8 kf = *reinterpret_cast<const short8*>(
            (char*)Ks + row * 128 + (((g + 4 * c) ^ (row & 7)) << 4));
        sacc[mt] =
            __builtin_amdgcn_mfma_f32_16x16x32_bf16(kf, qf[c], sacc[mt], 0, 0, 0);
      }
    }

    float tmax = -1e30f;
    #pragma unroll
    for (int s = 0; s < 4; s++)
      #pragma unroll
      for (int r = 0; r < 4; r++) tmax = fmaxf(tmax, sacc[s][r]);
    tmax = fmaxf(tmax, __shfl_xor(tmax, 16));
    tmax = fmaxf(tmax, __shfl_xor(tmax, 32));
    const float mnew = fmaxf(m_run, tmax);
    const float alpha = __builtin_amdgcn_exp2f((m_run - mnew) * SM_SCALE);
    m_run = mnew;
    float wgt[4][4];
    float wsum = 0.f;
    #pragma unroll
    for (int s = 0; s < 4; s++)
      #pragma unroll
      for (int r = 0; r < 4; r++) {
        wgt[s][r] = __builtin_amdgcn_exp2f((sacc[s][r] - mnew) * SM_SCALE);
        wsum += wgt[s][r];
      }
    l_run = l_run * alpha + wsum;

    float ar[4];
    #pragma unroll
    for (int r = 0; r < 4; r++) ar[r] = __shfl(alpha, g * 4 + r);
    #pragma unroll
    for (int dt = 0; dt < 4; dt++)
      #pragma unroll
      for (int r = 0; r < 4; r++) Oacc[dt][r] *= ar[r];

    short8 pa[2];
    #pragma unroll
    for (int c = 0; c < 2; c++)
      #pragma unroll
      for (int i = 0; i < 8; i++) pa[c][i] = f2bf(wgt[2 * c + (i >> 2)][i & 3]);

    #pragma unroll
    for (int dt = 0; dt < 4; dt++) {
      const int row = dt * 16 + l15;
      const int rb2 = row * 128;
      const int sw = row & 7;
      const int gl = (g & 1) * 8;
      const int gh = g >> 1;
      #pragma unroll
      for (int c = 0; c < 2; c++) {
        const short4v v0 = *reinterpret_cast<const short4v*>(
            (char*)Vs + rb2 + ((((4 * c + 0) + gh) ^ sw) << 4) + gl);
        const short4v v1 = *reinterpret_cast<const short4v*>(
            (char*)Vs + rb2 + ((((4 * c + 2) + gh) ^ sw) << 4) + gl);
        const short8 vf =
            __builtin_shufflevector(v0, v1, 0, 1, 2, 3, 4, 5, 6, 7);
        Oacc[dt] =
            __builtin_amdgcn_mfma_f32_16x16x32_bf16(pa[c], vf, Oacc[dt], 0, 0, 0);
      }
    }
  }

  l_run += __shfl_xor(l_run, 16);
  l_run += __shfl_xor(l_run, 32);
  float linv[4];
  #pragma unroll
  for (int r = 0; r < 4; r++) linv[r] = 1.0f / __shfl(l_run, g * 4 + r);

  const int b_ = bh / Hc, h_ = bh % Hc;
  #pragma unroll
  for (int dt = 0; dt < 4; dt++)
    #pragma unroll
    for (int r = 0; r < 4; r++) {
      const int qa = qbase + g * 4 + r;
      float* p = ctx + ((size_t)(b_ * Sc + qa)) * Dc + h_ * 64 + dt * 16 + l15;
      *p = Oacc[dt][r] * linv[r];
    }
}

// ---------------------------------------------------------------------------
extern "C" void kernel_launch(void* const* d_in, const int* in_sizes, int n_in,
                              void* d_out, int out_size, void* d_ws,
                              size_t ws_size, hipStream_t stream) {
  const float* query = (const float*)d_in[0];
  const float* key_  = (const float*)d_in[1];
  const float* value = (const float*)d_in[2];
  const float* Wq = (const float*)d_in[3];
  const float* bq = (const float*)d_in[4];
  const float* Wk = (const float*)d_in[5];
  const float* bk = (const float*)d_in[6];
  const float* Wv = (const float*)d_in[7];
  const float* bv = (const float*)d_in[8];
  const float* Wd = (const float*)d_in[9];
  const float* bd = (const float*)d_in[10];

  float* out = (float*)d_out;
  float* hidden = out;                 // [B,S,D] fp32
  float* context = out + OUT_ELEMS;    // [B,S,D] fp32

  __hip_bfloat16* Qw  = (__hip_bfloat16*)d_ws;       // [B,H,S,DK]
  __hip_bfloat16* Kw  = Qw + HEAD_ELEMS;             // [B,H,S,DK]
  __hip_bfloat16* Vtw = Kw + HEAD_ELEMS;             // [B,H,DK,S]
  __hip_bfloat16* WtQ = Vtw + HEAD_ELEMS;            // [N=768][K=768]
  __hip_bfloat16* WtK = WtQ + (size_t)Dc * Dc;
  __hip_bfloat16* WtV = WtK + (size_t)Dc * Dc;
  __hip_bfloat16* WtD = WtV + (size_t)Dc * Dc;
  // total ws: 3*12.58 MB + 4*1.125 MB = 42.5 MB (round-1 used 75.5 MB OK)

  const dim3 wgrid(Dc / 32, Dc / 32);  // 24 x 24
  wtrans<<<wgrid, 256, 0, stream>>>(Wq, WtQ);
  wtrans<<<wgrid, 256, 0, stream>>>(Wk, WtK);
  wtrans<<<wgrid, 256, 0, stream>>>(Wv, WtV);
  wtrans<<<wgrid, 256, 0, stream>>>(Wd, WtD);

  const int ggrid = (BSc / 128) * (Dc / 128);  // 64 * 6 = 384
  gemm_mfma<0><<<ggrid, 256, 0, stream>>>(query, WtQ, bq, Qw);
  gemm_mfma<0><<<ggrid, 256, 0, stream>>>(key_, WtK, bk, Kw);
  gemm_mfma<2><<<ggrid, 256, 0, stream>>>(value, WtV, bv, Vtw);

  attn_mfma<<<Bc * Hc * (Sc / 64), 256, 0, stream>>>(Qw, Kw, Vtw, context);

  gemm_mfma<1><<<ggrid, 256, 0, stream>>>(context, WtD, bd, hidden);
}

// Round 10
// 289.417 us; speedup vs baseline: 9.1607x; 1.0389x over previous
//
#include <hip/hip_runtime.h>
#include <hip/hip_bf16.h>
#include <math.h>

// Problem constants
constexpr int Bc = 8;
constexpr int Sc = 1024;
constexpr int Dc = 768;
constexpr int Hc = 12;
constexpr int DKc = 64;
constexpr int BSc = Bc * Sc;          // 8192 rows
constexpr size_t HEAD_ELEMS = (size_t)Bc * Hc * Sc * DKc;  // 6291456
constexpr size_t OUT_ELEMS  = (size_t)Bc * Sc * Dc;        // 6291456

typedef __attribute__((ext_vector_type(8))) short short8;
typedef __attribute__((ext_vector_type(4))) short short4v;
typedef __attribute__((ext_vector_type(4))) float f32x4;

__device__ __forceinline__ short f2bf(float x) {
  __hip_bfloat16 h = __float2bfloat16(x);
  short r;
  __builtin_memcpy(&r, &h, 2);
  return r;
}

// async global->LDS, 16B per lane. LDS dest = wave-uniform base + lane*16.
__device__ __forceinline__ void gload16(const void* g, void* l) {
  __builtin_amdgcn_global_load_lds(
      (const __attribute__((address_space(1))) void*)g,
      (__attribute__((address_space(3))) void*)l, 16, 0, 0);
}

// ---------------------------------------------------------------------------
// Fused weight transpose+cast: Wt[z][n][k] bf16 = W_z[k][n] fp32.
// Grid (24,24,4), 256 threads.
// ---------------------------------------------------------------------------
__global__ __launch_bounds__(256) void wtrans4(
    const float* __restrict__ W0, const float* __restrict__ W1,
    const float* __restrict__ W2, const float* __restrict__ W3,
    __hip_bfloat16* __restrict__ Wt0) {
  __shared__ float t[32][33];
  const int z = blockIdx.z;
  const float* W = (z == 0) ? W0 : (z == 1) ? W1 : (z == 2) ? W2 : W3;
  __hip_bfloat16* Wt = Wt0 + (size_t)z * Dc * Dc;
  const int tx = threadIdx.x & 31, ty = threadIdx.x >> 5;
  const int bx = blockIdx.x * 32;   // n-base
  const int by = blockIdx.y * 32;   // k-base
  #pragma unroll
  for (int i = 0; i < 32; i += 8)
    t[ty + i][tx] = W[(size_t)(by + ty + i) * Dc + bx + tx];
  __syncthreads();
  #pragma unroll
  for (int i = 0; i < 32; i += 8)
    Wt[(size_t)(bx + ty + i) * Dc + by + tx] = __float2bfloat16(t[tx][ty + i]);
}

// ---------------------------------------------------------------------------
// Fused QKV BF16 MFMA GEMM.  Grid (384, 3): y = projection (0=Q,1=K,2=V).
// C[8192,768] = A[8192,768](fp32) @ Wt_y[768,768](bf16)^T + bias_y
// 128x128 tile, BK=64, 4 waves (2x2), 64x64 per wave, 2-barrier K-loop.
// B via global_load_lds (linear LDS); A reg-staged fp32->bf16 (fused cast).
// Epilogue (wave-uniform switch):
//   proj 0/1: bf16 head-split [B,H,S,DK]
//   proj 2:   bf16 transposed [B,H,DK,S], short4 packed along S
// ---------------------------------------------------------------------------
__global__ __launch_bounds__(256) void gemm_qkv(
    const float* __restrict__ Aq, const float* __restrict__ Ak,
    const float* __restrict__ Av, const __hip_bfloat16* __restrict__ Wt0,
    const float* __restrict__ bq, const float* __restrict__ bk,
    const float* __restrict__ bv, __hip_bfloat16* __restrict__ out0) {
  __shared__ __hip_bfloat16 As[128 * 64];   // 16 KB, [m][k] linear
  __shared__ __hip_bfloat16 Bs[128 * 64];   // 16 KB, [n][k] linear

  const int tid = threadIdx.x;
  const int lane = tid & 63;
  const int wv = tid >> 6;
  const int l15 = lane & 15;
  const int g = lane >> 4;
  const int wr = wv >> 1, wc = wv & 1;

  const int proj = blockIdx.y;
  const float* A = (proj == 0) ? Aq : (proj == 1) ? Ak : Av;
  const float* bias = (proj == 0) ? bq : (proj == 1) ? bk : bv;
  const __hip_bfloat16* Wt = Wt0 + (size_t)proj * Dc * Dc;
  __hip_bfloat16* out = out0 + (size_t)proj * HEAD_ELEMS;

  // XCD swizzle within the 384-block slice (384 % 8 == 0 -> bijective)
  const int orig = blockIdx.x;
  const int swz = (orig & 7) * 48 + (orig >> 3);
  const int rb = swz / (Dc / 128);
  const int cb = swz % (Dc / 128);
  const int row0 = rb * 128, col0 = cb * 128;

  f32x4 acc[4][4];
  #pragma unroll
  for (int ai = 0; ai < 4; ai++)
    #pragma unroll
    for (int bj = 0; bj < 4; bj++) acc[ai][bj] = f32x4{0.f, 0.f, 0.f, 0.f};

  for (int k0 = 0; k0 < Dc; k0 += 64) {
    __syncthreads();

    // ---- B tile: 4 async calls/wave ----
    #pragma unroll
    for (int j = 0; j < 4; j++) {
      const int r = j * 32 + wv * 8 + (lane >> 3);
      const __hip_bfloat16* gp =
          Wt + (size_t)(col0 + r) * Dc + k0 + (lane & 7) * 8;
      gload16(gp, &Bs[(j * 32 + wv * 8) * 64]);
    }

    // ---- A tile: reg-staged fp32 -> bf16 ----
    #pragma unroll
    for (int i = 0; i < 4; i++) {
      const int id = tid + i * 256;
      const int r = id >> 3, gi = id & 7;
      const float* ap = A + (size_t)(row0 + r) * Dc + k0 + gi * 8;
      const float4 f0 = *reinterpret_cast<const float4*>(ap);
      const float4 f1 = *reinterpret_cast<const float4*>(ap + 4);
      short8 s;
      s[0] = f2bf(f0.x); s[1] = f2bf(f0.y); s[2] = f2bf(f0.z); s[3] = f2bf(f0.w);
      s[4] = f2bf(f1.x); s[5] = f2bf(f1.y); s[6] = f2bf(f1.z); s[7] = f2bf(f1.w);
      *reinterpret_cast<short8*>(&As[r * 64 + gi * 8]) = s;
    }
    __syncthreads();

    #pragma unroll
    for (int kk = 0; kk < 2; kk++) {
      short8 a[4], b[4];
      #pragma unroll
      for (int ai = 0; ai < 4; ai++)
        a[ai] = *reinterpret_cast<const short8*>(
            &As[(wr * 64 + ai * 16 + l15) * 64 + kk * 32 + g * 8]);
      #pragma unroll
      for (int bj = 0; bj < 4; bj++)
        b[bj] = *reinterpret_cast<const short8*>(
            &Bs[(wc * 64 + bj * 16 + l15) * 64 + kk * 32 + g * 8]);
      #pragma unroll
      for (int ai = 0; ai < 4; ai++)
        #pragma unroll
        for (int bj = 0; bj < 4; bj++)
          acc[ai][bj] = __builtin_amdgcn_mfma_f32_16x16x32_bf16(
              a[ai], b[bj], acc[ai][bj], 0, 0, 0);
    }
  }

  // ---- epilogue.  C/D map: col=lane&15 (n), row=g*4+reg (m) ----
  const int mb = row0 + wr * 64, nb = col0 + wc * 64;
  if (proj < 2) {
    // head-split [B,H,S,DK]: per-element 2B stores, dk=l15 coalesced
    #pragma unroll
    for (int ai = 0; ai < 4; ai++)
      #pragma unroll
      for (int bj = 0; bj < 4; bj++) {
        const int n = nb + bj * 16 + l15;
        const int h_ = n >> 6, dk = n & 63;
        const float bn = bias[n];
        #pragma unroll
        for (int reg = 0; reg < 4; reg++) {
          const int m = mb + ai * 16 + g * 4 + reg;
          const int b_ = m >> 10, s_ = m & 1023;
          out[(((size_t)(b_ * Hc + h_)) * Sc + s_) * DKc + dk] =
              __float2bfloat16(acc[ai][bj][reg] + bn);
        }
      }
  } else {
    // transposed [B,H,DK,S]: 4 regs = 4 consecutive s -> one short4 store
    #pragma unroll
    for (int ai = 0; ai < 4; ai++)
      #pragma unroll
      for (int bj = 0; bj < 4; bj++) {
        const int n = nb + bj * 16 + l15;          // d index
        const int h_ = n >> 6, dk = n & 63;
        const float bn = bias[n];
        const int m0 = mb + ai * 16 + g * 4;       // s base (mult of 4)
        const int b_ = m0 >> 10, s0 = m0 & 1023;
        short4v sv;
        sv[0] = f2bf(acc[ai][bj][0] + bn);
        sv[1] = f2bf(acc[ai][bj][1] + bn);
        sv[2] = f2bf(acc[ai][bj][2] + bn);
        sv[3] = f2bf(acc[ai][bj][3] + bn);
        *reinterpret_cast<short4v*>(
            &out[(((size_t)(b_ * Hc + h_)) * DKc + dk) * Sc + s0]) = sv;
      }
  }
}

// ---------------------------------------------------------------------------
// Output projection: hidden[8192,768] fp32 = context @ WtD^T + bd.
// BM=128, BN=64, BK=64 -> grid 64*12 = 768 blocks (2x parallelism of 128x128).
// 4 waves 2x2: per-wave 64x32, acc[4][2].
// ---------------------------------------------------------------------------
__global__ __launch_bounds__(256) void gemm_out(
    const float* __restrict__ A, const __hip_bfloat16* __restrict__ Wt,
    const float* __restrict__ bias, float* __restrict__ out) {
  __shared__ __hip_bfloat16 As[128 * 64];   // 16 KB
  __shared__ __hip_bfloat16 Bs[64 * 64];    // 8 KB

  const int tid = threadIdx.x;
  const int lane = tid & 63;
  const int wv = tid >> 6;
  const int l15 = lane & 15;
  const int g = lane >> 4;
  const int wr = wv >> 1, wc = wv & 1;

  // XCD swizzle; nwg = 768 divisible by 8 -> bijective
  const int orig = blockIdx.x;
  const int swz = (orig & 7) * 96 + (orig >> 3);
  const int rb = swz / (Dc / 64);
  const int cb = swz % (Dc / 64);
  const int row0 = rb * 128, col0 = cb * 64;

  f32x4 acc[4][2];
  #pragma unroll
  for (int ai = 0; ai < 4; ai++)
    #pragma unroll
    for (int bj = 0; bj < 2; bj++) acc[ai][bj] = f32x4{0.f, 0.f, 0.f, 0.f};

  for (int k0 = 0; k0 < Dc; k0 += 64) {
    __syncthreads();

    // ---- B tile (64 rows): 2 async calls/wave ----
    #pragma unroll
    for (int j = 0; j < 2; j++) {
      const int r = j * 32 + wv * 8 + (lane >> 3);
      const __hip_bfloat16* gp =
          Wt + (size_t)(col0 + r) * Dc + k0 + (lane & 7) * 8;
      gload16(gp, &Bs[(j * 32 + wv * 8) * 64]);
    }

    // ---- A tile: reg-staged fp32 -> bf16 ----
    #pragma unroll
    for (int i = 0; i < 4; i++) {
      const int id = tid + i * 256;
      const int r = id >> 3, gi = id & 7;
      const float* ap = A + (size_t)(row0 + r) * Dc + k0 + gi * 8;
      const float4 f0 = *reinterpret_cast<const float4*>(ap);
      const float4 f1 = *reinterpret_cast<const float4*>(ap + 4);
      short8 s;
      s[0] = f2bf(f0.x); s[1] = f2bf(f0.y); s[2] = f2bf(f0.z); s[3] = f2bf(f0.w);
      s[4] = f2bf(f1.x); s[5] = f2bf(f1.y); s[6] = f2bf(f1.z); s[7] = f2bf(f1.w);
      *reinterpret_cast<short8*>(&As[r * 64 + gi * 8]) = s;
    }
    __syncthreads();

    #pragma unroll
    for (int kk = 0; kk < 2; kk++) {
      short8 a[4], b[2];
      #pragma unroll
      for (int ai = 0; ai < 4; ai++)
        a[ai] = *reinterpret_cast<const short8*>(
            &As[(wr * 64 + ai * 16 + l15) * 64 + kk * 32 + g * 8]);
      #pragma unroll
      for (int bj = 0; bj < 2; bj++)
        b[bj] = *reinterpret_cast<const short8*>(
            &Bs[(wc * 32 + bj * 16 + l15) * 64 + kk * 32 + g * 8]);
      #pragma unroll
      for (int ai = 0; ai < 4; ai++)
        #pragma unroll
        for (int bj = 0; bj < 2; bj++)
          acc[ai][bj] = __builtin_amdgcn_mfma_f32_16x16x32_bf16(
              a[ai], b[bj], acc[ai][bj], 0, 0, 0);
    }
  }

  const int mb = row0 + wr * 64, nb = col0 + wc * 32;
  #pragma unroll
  for (int ai = 0; ai < 4; ai++)
    #pragma unroll
    for (int bj = 0; bj < 2; bj++) {
      const int n = nb + bj * 16 + l15;
      const float bn = bias[n];
      #pragma unroll
      for (int reg = 0; reg < 4; reg++) {
        const int m = mb + ai * 16 + g * 4 + reg;
        out[(size_t)m * Dc + n] = acc[ai][bj][reg] + bn;
      }
    }
}

// ---------------------------------------------------------------------------
// BF16 MFMA flash attention (unchanged -- verified rounds 4/8).
// ---------------------------------------------------------------------------
__global__ __launch_bounds__(256) void attn_mfma(
    const __hip_bfloat16* __restrict__ Q, const __hip_bfloat16* __restrict__ K,
    const __hip_bfloat16* __restrict__ Vt, float* __restrict__ ctx) {
  __shared__ __hip_bfloat16 Ks[64 * 64];   // 8 KB
  __shared__ __hip_bfloat16 Vs[64 * 64];   // 8 KB, transposed tile [d][kv]

  const int tid = threadIdx.x;
  const int lane = tid & 63;
  const int w = tid >> 6;
  const int l15 = lane & 15;
  const int g = lane >> 4;

  const int cpx = gridDim.x >> 3;
  const int bid = blockIdx.x;
  const int wid = (bid & 7) * cpx + (bid >> 3);
  const int bh = wid >> 4;       // (b*H + h)
  const int qt = wid & 15;
  const int qbase = qt * 64 + w * 16;

  const __hip_bfloat16* Qb = Q + (size_t)bh * Sc * DKc;
  const __hip_bfloat16* Kb = K + (size_t)bh * Sc * DKc;
  const __hip_bfloat16* Vtb = Vt + (size_t)bh * DKc * Sc;  // [64][1024]

  short8 qf[2];
  {
    const __hip_bfloat16* qp = Qb + (size_t)(qbase + l15) * DKc + g * 8;
    qf[0] = *reinterpret_cast<const short8*>(qp);
    qf[1] = *reinterpret_cast<const short8*>(qp + 32);
  }

  f32x4 Oacc[4];
  #pragma unroll
  for (int dt = 0; dt < 4; dt++) Oacc[dt] = f32x4{0.f, 0.f, 0.f, 0.f};
  float m_run = -1e30f, l_run = 0.f;

  constexpr float SM_SCALE = 0.125f * 1.44269504088896340736f;

  for (int kt = 0; kt < Sc; kt += 64) {
    __syncthreads();
    #pragma unroll
    for (int it = 0; it < 2; it++) {
      const int tt = tid + it * 256;
      const int row = tt >> 3, s = tt & 7;
      const float4 kv = *reinterpret_cast<const float4*>(
          Kb + (size_t)(kt + row) * DKc + s * 8);
      const float4 vv = *reinterpret_cast<const float4*>(
          Vtb + (size_t)row * Sc + kt + s * 8);
      const int off = row * 128 + ((s ^ (row & 7)) << 4);
      *reinterpret_cast<float4*>((char*)Ks + off) = kv;
      *reinterpret_cast<float4*>((char*)Vs + off) = vv;
    }
    __syncthreads();

    f32x4 sacc[4];
    #pragma unroll
    for (int mt = 0; mt < 4; mt++) sacc[mt] = f32x4{0.f, 0.f, 0.f, 0.f};
    #pragma unroll
    for (int c = 0; c < 2; c++) {
      #pragma unroll
      for (int mt = 0; mt < 4; mt++) {
        const int row = mt * 16 + l15;
        const short8 kf = *reinterpret_cast<const short8*>(
            (char*)Ks + row * 128 + (((g + 4 * c) ^ (row & 7)) << 4));
        sacc[mt] =
            __builtin_amdgcn_mfma_f32_16x16x32_bf16(kf, qf[c], sacc[mt], 0, 0, 0);
      }
    }

    float tmax = -1e30f;
    #pragma unroll
    for (int s = 0; s < 4; s++)
      #pragma unroll
      for (int r = 0; r < 4; r++) tmax = fmaxf(tmax, sacc[s][r]);
    tmax = fmaxf(tmax, __shfl_xor(tmax, 16));
    tmax = fmaxf(tmax, __shfl_xor(tmax, 32));
    const float mnew = fmaxf(m_run, tmax);
    const float alpha = __builtin_amdgcn_exp2f((m_run - mnew) * SM_SCALE);
    m_run = mnew;
    float wgt[4][4];
    float wsum = 0.f;
    #pragma unroll
    for (int s = 0; s < 4; s++)
      #pragma unroll
      for (int r = 0; r < 4; r++) {
        wgt[s][r] = __builtin_amdgcn_exp2f((sacc[s][r] - mnew) * SM_SCALE);
        wsum += wgt[s][r];
      }
    l_run = l_run * alpha + wsum;

    float ar[4];
    #pragma unroll
    for (int r = 0; r < 4; r++) ar[r] = __shfl(alpha, g * 4 + r);
    #pragma unroll
    for (int dt = 0; dt < 4; dt++)
      #pragma unroll
      for (int r = 0; r < 4; r++) Oacc[dt][r] *= ar[r];

    short8 pa[2];
    #pragma unroll
    for (int c = 0; c < 2; c++)
      #pragma unroll
      for (int i = 0; i < 8; i++) pa[c][i] = f2bf(wgt[2 * c + (i >> 2)][i & 3]);

    #pragma unroll
    for (int dt = 0; dt < 4; dt++) {
      const int row = dt * 16 + l15;
      const int rb2 = row * 128;
      const int sw = row & 7;
      const int gl = (g & 1) * 8;
      const int gh = g >> 1;
      #pragma unroll
      for (int c = 0; c < 2; c++) {
        const short4v v0 = *reinterpret_cast<const short4v*>(
            (char*)Vs + rb2 + ((((4 * c + 0) + gh) ^ sw) << 4) + gl);
        const short4v v1 = *reinterpret_cast<const short4v*>(
            (char*)Vs + rb2 + ((((4 * c + 2) + gh) ^ sw) << 4) + gl);
        const short8 vf =
            __builtin_shufflevector(v0, v1, 0, 1, 2, 3, 4, 5, 6, 7);
        Oacc[dt] =
            __builtin_amdgcn_mfma_f32_16x16x32_bf16(pa[c], vf, Oacc[dt], 0, 0, 0);
      }
    }
  }

  l_run += __shfl_xor(l_run, 16);
  l_run += __shfl_xor(l_run, 32);
  float linv[4];
  #pragma unroll
  for (int r = 0; r < 4; r++) linv[r] = 1.0f / __shfl(l_run, g * 4 + r);

  const int b_ = bh / Hc, h_ = bh % Hc;
  #pragma unroll
  for (int dt = 0; dt < 4; dt++)
    #pragma unroll
    for (int r = 0; r < 4; r++) {
      const int qa = qbase + g * 4 + r;
      float* p = ctx + ((size_t)(b_ * Sc + qa)) * Dc + h_ * 64 + dt * 16 + l15;
      *p = Oacc[dt][r] * linv[r];
    }
}

// ---------------------------------------------------------------------------
extern "C" void kernel_launch(void* const* d_in, const int* in_sizes, int n_in,
                              void* d_out, int out_size, void* d_ws,
                              size_t ws_size, hipStream_t stream) {
  const float* query = (const float*)d_in[0];
  const float* key_  = (const float*)d_in[1];
  const float* value = (const float*)d_in[2];
  const float* Wq = (const float*)d_in[3];
  const float* bq = (const float*)d_in[4];
  const float* Wk = (const float*)d_in[5];
  const float* bk = (const float*)d_in[6];
  const float* Wv = (const float*)d_in[7];
  const float* bv = (const float*)d_in[8];
  const float* Wd = (const float*)d_in[9];
  const float* bd = (const float*)d_in[10];

  float* out = (float*)d_out;
  float* hidden = out;                 // [B,S,D] fp32
  float* context = out + OUT_ELEMS;    // [B,S,D] fp32

  __hip_bfloat16* Qw  = (__hip_bfloat16*)d_ws;       // [B,H,S,DK]
  __hip_bfloat16* Kw  = Qw + HEAD_ELEMS;             // [B,H,S,DK]
  __hip_bfloat16* Vtw = Kw + HEAD_ELEMS;             // [B,H,DK,S]
  __hip_bfloat16* WtQ = Vtw + HEAD_ELEMS;            // [4][N=768][K=768]
  __hip_bfloat16* WtD = WtQ + 3 * (size_t)Dc * Dc;

  // fused weight transpose+cast (W order: Wq, Wk, Wv, Wd contiguous)
  wtrans4<<<dim3(Dc / 32, Dc / 32, 4), 256, 0, stream>>>(Wq, Wk, Wv, Wd, WtQ);

  // fused QKV projections: 3 x 384 = 1152 blocks in one dispatch
  gemm_qkv<<<dim3((BSc / 128) * (Dc / 128), 3), 256, 0, stream>>>(
      query, key_, value, WtQ, bq, bk, bv, Qw);

  attn_mfma<<<Bc * Hc * (Sc / 64), 256, 0, stream>>>(Qw, Kw, Vtw, context);

  // output projection: 128x64 tiles -> 768 blocks
  gemm_out<<<(BSc / 128) * (Dc / 64), 256, 0, stream>>>(
      context, WtD, bd, hidden);
}

// Round 11
// 271.007 us; speedup vs baseline: 9.7831x; 1.0679x over previous
//
#include <hip/hip_runtime.h>
#include <hip/hip_bf16.h>
#include <math.h>

// Problem constants
constexpr int Bc = 8;
constexpr int Sc = 1024;
constexpr int Dc = 768;
constexpr int Hc = 12;
constexpr int DKc = 64;
constexpr int BSc = Bc * Sc;          // 8192 rows
constexpr size_t HEAD_ELEMS = (size_t)Bc * Hc * Sc * DKc;  // 6291456
constexpr size_t OUT_ELEMS  = (size_t)Bc * Sc * Dc;        // 6291456

typedef __attribute__((ext_vector_type(8))) short short8;
typedef __attribute__((ext_vector_type(4))) short short4v;
typedef __attribute__((ext_vector_type(4))) float f32x4;

__device__ __forceinline__ short f2bf(float x) {
  __hip_bfloat16 h = __float2bfloat16(x);
  short r;
  __builtin_memcpy(&r, &h, 2);
  return r;
}

// async global->LDS, 16B per lane. LDS dest = wave-uniform base + lane*16.
__device__ __forceinline__ void gload16(const void* g, void* l) {
  __builtin_amdgcn_global_load_lds(
      (const __attribute__((address_space(1))) void*)g,
      (__attribute__((address_space(3))) void*)l, 16, 0, 0);
}

// ---------------------------------------------------------------------------
// Input cast: fp32 -> bf16, one short8 per thread.  Grid (3072, 3).
// ---------------------------------------------------------------------------
__global__ __launch_bounds__(256) void cast3(
    const float* __restrict__ q, const float* __restrict__ k,
    const float* __restrict__ v, __hip_bfloat16* __restrict__ dq,
    __hip_bfloat16* __restrict__ dk, __hip_bfloat16* __restrict__ dv) {
  const int which = blockIdx.y;
  const float* src = (which == 0) ? q : (which == 1) ? k : v;
  __hip_bfloat16* dst = (which == 0) ? dq : (which == 1) ? dk : dv;
  const size_t i = ((size_t)blockIdx.x * 256 + threadIdx.x) * 8;
  const float4 f0 = *reinterpret_cast<const float4*>(src + i);
  const float4 f1 = *reinterpret_cast<const float4*>(src + i + 4);
  short8 s;
  s[0] = f2bf(f0.x); s[1] = f2bf(f0.y); s[2] = f2bf(f0.z); s[3] = f2bf(f0.w);
  s[4] = f2bf(f1.x); s[5] = f2bf(f1.y); s[6] = f2bf(f1.z); s[7] = f2bf(f1.w);
  *reinterpret_cast<short8*>(dst + i) = s;
}

// ---------------------------------------------------------------------------
// Fused weight transpose+cast: Wt[z][n][k] bf16 = W_z[k][n] fp32.
// Grid (24,24,4), 256 threads.
// ---------------------------------------------------------------------------
__global__ __launch_bounds__(256) void wtrans4(
    const float* __restrict__ W0, const float* __restrict__ W1,
    const float* __restrict__ W2, const float* __restrict__ W3,
    __hip_bfloat16* __restrict__ Wt0) {
  __shared__ float t[32][33];
  const int z = blockIdx.z;
  const float* W = (z == 0) ? W0 : (z == 1) ? W1 : (z == 2) ? W2 : W3;
  __hip_bfloat16* Wt = Wt0 + (size_t)z * Dc * Dc;
  const int tx = threadIdx.x & 31, ty = threadIdx.x >> 5;
  const int bx = blockIdx.x * 32;   // n-base
  const int by = blockIdx.y * 32;   // k-base
  #pragma unroll
  for (int i = 0; i < 32; i += 8)
    t[ty + i][tx] = W[(size_t)(by + ty + i) * Dc + bx + tx];
  __syncthreads();
  #pragma unroll
  for (int i = 0; i < 32; i += 8)
    Wt[(size_t)(bx + ty + i) * Dc + by + tx] = __float2bfloat16(t[tx][ty + i]);
}

// ---------------------------------------------------------------------------
// Pipelined 2-phase BF16 GEMM core: 128x128 tile, BK=32, NT=24 K-steps,
// 4 waves (2x2), 64x64 per wave.  Both tiles via global_load_lds into
// static double-buffered LDS (4 x 8 KB).  Next-tile stage issued BEFORE
// current compute; __syncthreads() drains vmcnt after compute (T3 minimum).
// ---------------------------------------------------------------------------
__device__ __forceinline__ void stage_tiles(
    const __hip_bfloat16* A, const __hip_bfloat16* Wt, int row0, int col0,
    int k0, int wv, int lane, __hip_bfloat16* bufA, __hip_bfloat16* bufB) {
  #pragma unroll
  for (int j = 0; j < 2; j++) {
    const int rr = j * 64 + wv * 16;
    const int r = rr + (lane >> 2);
    const int kc = k0 + (lane & 3) * 8;
    gload16(A + (size_t)(row0 + r) * Dc + kc, bufA + rr * 32);
    gload16(Wt + (size_t)(col0 + r) * Dc + kc, bufB + rr * 32);
  }
}

__device__ __forceinline__ void compute_tiles(
    const __hip_bfloat16* bufA, const __hip_bfloat16* bufB, int wr, int wc,
    int l15, int g, f32x4 (&acc)[4][4]) {
  short8 a[4], b[4];
  #pragma unroll
  for (int ai = 0; ai < 4; ai++)
    a[ai] = *reinterpret_cast<const short8*>(
        &bufA[(wr * 64 + ai * 16 + l15) * 32 + g * 8]);
  #pragma unroll
  for (int bj = 0; bj < 4; bj++)
    b[bj] = *reinterpret_cast<const short8*>(
        &bufB[(wc * 64 + bj * 16 + l15) * 32 + g * 8]);
  #pragma unroll
  for (int ai = 0; ai < 4; ai++)
    #pragma unroll
    for (int bj = 0; bj < 4; bj++)
      acc[ai][bj] = __builtin_amdgcn_mfma_f32_16x16x32_bf16(
          a[ai], b[bj], acc[ai][bj], 0, 0, 0);
}

#define GEMM_PIPELINE(A_, Wt_)                                          \
  stage_tiles(A_, Wt_, row0, col0, 0, wv, lane, As0, Bs0);              \
  __syncthreads();                                                      \
  for (int t = 0; t < 24; t += 2) {                                     \
    stage_tiles(A_, Wt_, row0, col0, (t + 1) * 32, wv, lane, As1, Bs1); \
    compute_tiles(As0, Bs0, wr, wc, l15, g, acc);                       \
    __syncthreads();                                                    \
    if (t + 2 < 24)                                                     \
      stage_tiles(A_, Wt_, row0, col0, (t + 2) * 32, wv, lane, As0, Bs0);\
    compute_tiles(As1, Bs1, wr, wc, l15, g, acc);                       \
    __syncthreads();                                                    \
  }

// ---------------------------------------------------------------------------
// Fused QKV GEMM.  Grid (384, 3): y = projection (0=Q,1=K,2=V).
// Epilogue: proj 0/1 -> bf16 head-split [B,H,S,DK]; proj 2 -> bf16
// transposed [B,H,DK,S] short4-packed along S (verified round 10).
// ---------------------------------------------------------------------------
__global__ __launch_bounds__(256) void gemm_qkv(
    const __hip_bfloat16* __restrict__ Aq, const __hip_bfloat16* __restrict__ Ak,
    const __hip_bfloat16* __restrict__ Av, const __hip_bfloat16* __restrict__ Wt0,
    const float* __restrict__ bq, const float* __restrict__ bk,
    const float* __restrict__ bv, __hip_bfloat16* __restrict__ out0) {
  __shared__ __hip_bfloat16 As0[128 * 32], Bs0[128 * 32];
  __shared__ __hip_bfloat16 As1[128 * 32], Bs1[128 * 32];

  const int tid = threadIdx.x;
  const int lane = tid & 63;
  const int wv = tid >> 6;
  const int l15 = lane & 15;
  const int g = lane >> 4;
  const int wr = wv >> 1, wc = wv & 1;

  const int proj = blockIdx.y;
  const __hip_bfloat16* A = (proj == 0) ? Aq : (proj == 1) ? Ak : Av;
  const float* bias = (proj == 0) ? bq : (proj == 1) ? bk : bv;
  const __hip_bfloat16* Wt = Wt0 + (size_t)proj * Dc * Dc;
  __hip_bfloat16* out = out0 + (size_t)proj * HEAD_ELEMS;

  // XCD swizzle (384 % 8 == 0 -> bijective)
  const int orig = blockIdx.x;
  const int swz = (orig & 7) * 48 + (orig >> 3);
  const int row0 = (swz / (Dc / 128)) * 128;
  const int col0 = (swz % (Dc / 128)) * 128;

  f32x4 acc[4][4];
  #pragma unroll
  for (int ai = 0; ai < 4; ai++)
    #pragma unroll
    for (int bj = 0; bj < 4; bj++) acc[ai][bj] = f32x4{0.f, 0.f, 0.f, 0.f};

  GEMM_PIPELINE(A, Wt)

  // ---- epilogue.  C/D map: col=lane&15 (n), row=g*4+reg (m) ----
  const int mb = row0 + wr * 64, nb = col0 + wc * 64;
  if (proj < 2) {
    #pragma unroll
    for (int ai = 0; ai < 4; ai++)
      #pragma unroll
      for (int bj = 0; bj < 4; bj++) {
        const int n = nb + bj * 16 + l15;
        const int h_ = n >> 6, dk = n & 63;
        const float bn = bias[n];
        #pragma unroll
        for (int reg = 0; reg < 4; reg++) {
          const int m = mb + ai * 16 + g * 4 + reg;
          const int b_ = m >> 10, s_ = m & 1023;
          out[(((size_t)(b_ * Hc + h_)) * Sc + s_) * DKc + dk] =
              __float2bfloat16(acc[ai][bj][reg] + bn);
        }
      }
  } else {
    #pragma unroll
    for (int ai = 0; ai < 4; ai++)
      #pragma unroll
      for (int bj = 0; bj < 4; bj++) {
        const int n = nb + bj * 16 + l15;          // d index
        const int h_ = n >> 6, dk = n & 63;
        const float bn = bias[n];
        const int m0 = mb + ai * 16 + g * 4;       // s base (mult of 4)
        const int b_ = m0 >> 10, s0 = m0 & 1023;
        short4v sv;
        sv[0] = f2bf(acc[ai][bj][0] + bn);
        sv[1] = f2bf(acc[ai][bj][1] + bn);
        sv[2] = f2bf(acc[ai][bj][2] + bn);
        sv[3] = f2bf(acc[ai][bj][3] + bn);
        *reinterpret_cast<short4v*>(
            &out[(((size_t)(b_ * Hc + h_)) * DKc + dk) * Sc + s0]) = sv;
      }
  }
}

// ---------------------------------------------------------------------------
// Output projection: hidden[8192,768] fp32 = ctx_bf @ WtD^T + bd.  Grid 384.
// ---------------------------------------------------------------------------
__global__ __launch_bounds__(256) void gemm_o(
    const __hip_bfloat16* __restrict__ A, const __hip_bfloat16* __restrict__ Wt,
    const float* __restrict__ bias, float* __restrict__ out) {
  __shared__ __hip_bfloat16 As0[128 * 32], Bs0[128 * 32];
  __shared__ __hip_bfloat16 As1[128 * 32], Bs1[128 * 32];

  const int tid = threadIdx.x;
  const int lane = tid & 63;
  const int wv = tid >> 6;
  const int l15 = lane & 15;
  const int g = lane >> 4;
  const int wr = wv >> 1, wc = wv & 1;

  const int orig = blockIdx.x;
  const int swz = (orig & 7) * 48 + (orig >> 3);
  const int row0 = (swz / (Dc / 128)) * 128;
  const int col0 = (swz % (Dc / 128)) * 128;

  f32x4 acc[4][4];
  #pragma unroll
  for (int ai = 0; ai < 4; ai++)
    #pragma unroll
    for (int bj = 0; bj < 4; bj++) acc[ai][bj] = f32x4{0.f, 0.f, 0.f, 0.f};

  GEMM_PIPELINE(A, Wt)

  const int mb = row0 + wr * 64, nb = col0 + wc * 64;
  #pragma unroll
  for (int ai = 0; ai < 4; ai++)
    #pragma unroll
    for (int bj = 0; bj < 4; bj++) {
      const int n = nb + bj * 16 + l15;
      const float bn = bias[n];
      #pragma unroll
      for (int reg = 0; reg < 4; reg++) {
        const int m = mb + ai * 16 + g * 4 + reg;
        out[(size_t)m * Dc + n] = acc[ai][bj][reg] + bn;
      }
    }
}

// ---------------------------------------------------------------------------
// BF16 MFMA flash attention (verified rounds 4/8/10) + bf16 context
// side-write for the output projection.
// ---------------------------------------------------------------------------
__global__ __launch_bounds__(256) void attn_mfma(
    const __hip_bfloat16* __restrict__ Q, const __hip_bfloat16* __restrict__ K,
    const __hip_bfloat16* __restrict__ Vt, float* __restrict__ ctx,
    __hip_bfloat16* __restrict__ ctxb) {
  __shared__ __hip_bfloat16 Ks[64 * 64];   // 8 KB
  __shared__ __hip_bfloat16 Vs[64 * 64];   // 8 KB, transposed tile [d][kv]

  const int tid = threadIdx.x;
  const int lane = tid & 63;
  const int w = tid >> 6;
  const int l15 = lane & 15;
  const int g = lane >> 4;

  const int cpx = gridDim.x >> 3;
  const int bid = blockIdx.x;
  const int wid = (bid & 7) * cpx + (bid >> 3);
  const int bh = wid >> 4;       // (b*H + h)
  const int qt = wid & 15;
  const int qbase = qt * 64 + w * 16;

  const __hip_bfloat16* Qb = Q + (size_t)bh * Sc * DKc;
  const __hip_bfloat16* Kb = K + (size_t)bh * Sc * DKc;
  const __hip_bfloat16* Vtb = Vt + (size_t)bh * DKc * Sc;  // [64][1024]

  short8 qf[2];
  {
    const __hip_bfloat16* qp = Qb + (size_t)(qbase + l15) * DKc + g * 8;
    qf[0] = *reinterpret_cast<const short8*>(qp);
    qf[1] = *reinterpret_cast<const short8*>(qp + 32);
  }

  f32x4 Oacc[4];
  #pragma unroll
  for (int dt = 0; dt < 4; dt++) Oacc[dt] = f32x4{0.f, 0.f, 0.f, 0.f};
  float m_run = -1e30f, l_run = 0.f;

  constexpr float SM_SCALE = 0.125f * 1.44269504088896340736f;

  for (int kt = 0; kt < Sc; kt += 64) {
    __syncthreads();
    #pragma unroll
    for (int it = 0; it < 2; it++) {
      const int tt = tid + it * 256;
      const int row = tt >> 3, s = tt & 7;
      const float4 kv = *reinterpret_cast<const float4*>(
          Kb + (size_t)(kt + row) * DKc + s * 8);
      const float4 vv = *reinterpret_cast<const float4*>(
          Vtb + (size_t)row * Sc + kt + s * 8);
      const int off = row * 128 + ((s ^ (row & 7)) << 4);
      *reinterpret_cast<float4*>((char*)Ks + off) = kv;
      *reinterpret_cast<float4*>((char*)Vs + off) = vv;
    }
    __syncthreads();

    f32x4 sacc[4];
    #pragma unroll
    for (int mt = 0; mt < 4; mt++) sacc[mt] = f32x4{0.f, 0.f, 0.f, 0.f};
    #pragma unroll
    for (int c = 0; c < 2; c++) {
      #pragma unroll
      for (int mt = 0; mt < 4; mt++) {
        const int row = mt * 16 + l15;
        const short8 kf = *reinterpret_cast<const short8*>(
            (char*)Ks + row * 128 + (((g + 4 * c) ^ (row & 7)) << 4));
        sacc[mt] =
            __builtin_amdgcn_mfma_f32_16x16x32_bf16(kf, qf[c], sacc[mt], 0, 0, 0);
      }
    }

    float tmax = -1e30f;
    #pragma unroll
    for (int s = 0; s < 4; s++)
      #pragma unroll
      for (int r = 0; r < 4; r++) tmax = fmaxf(tmax, sacc[s][r]);
    tmax = fmaxf(tmax, __shfl_xor(tmax, 16));
    tmax = fmaxf(tmax, __shfl_xor(tmax, 32));
    const float mnew = fmaxf(m_run, tmax);
    const float alpha = __builtin_amdgcn_exp2f((m_run - mnew) * SM_SCALE);
    m_run = mnew;
    float wgt[4][4];
    float wsum = 0.f;
    #pragma unroll
    for (int s = 0; s < 4; s++)
      #pragma unroll
      for (int r = 0; r < 4; r++) {
        wgt[s][r] = __builtin_amdgcn_exp2f((sacc[s][r] - mnew) * SM_SCALE);
        wsum += wgt[s][r];
      }
    l_run = l_run * alpha + wsum;

    float ar[4];
    #pragma unroll
    for (int r = 0; r < 4; r++) ar[r] = __shfl(alpha, g * 4 + r);
    #pragma unroll
    for (int dt = 0; dt < 4; dt++)
      #pragma unroll
      for (int r = 0; r < 4; r++) Oacc[dt][r] *= ar[r];

    short8 pa[2];
    #pragma unroll
    for (int c = 0; c < 2; c++)
      #pragma unroll
      for (int i = 0; i < 8; i++) pa[c][i] = f2bf(wgt[2 * c + (i >> 2)][i & 3]);

    #pragma unroll
    for (int dt = 0; dt < 4; dt++) {
      const int row = dt * 16 + l15;
      const int rb2 = row * 128;
      const int sw = row & 7;
      const int gl = (g & 1) * 8;
      const int gh = g >> 1;
      #pragma unroll
      for (int c = 0; c < 2; c++) {
        const short4v v0 = *reinterpret_cast<const short4v*>(
            (char*)Vs + rb2 + ((((4 * c + 0) + gh) ^ sw) << 4) + gl);
        const short4v v1 = *reinterpret_cast<const short4v*>(
            (char*)Vs + rb2 + ((((4 * c + 2) + gh) ^ sw) << 4) + gl);
        const short8 vf =
            __builtin_shufflevector(v0, v1, 0, 1, 2, 3, 4, 5, 6, 7);
        Oacc[dt] =
            __builtin_amdgcn_mfma_f32_16x16x32_bf16(pa[c], vf, Oacc[dt], 0, 0, 0);
      }
    }
  }

  l_run += __shfl_xor(l_run, 16);
  l_run += __shfl_xor(l_run, 32);
  float linv[4];
  #pragma unroll
  for (int r = 0; r < 4; r++) linv[r] = 1.0f / __shfl(l_run, g * 4 + r);

  const int b_ = bh / Hc, h_ = bh % Hc;
  #pragma unroll
  for (int dt = 0; dt < 4; dt++)
    #pragma unroll
    for (int r = 0; r < 4; r++) {
      const int qa = qbase + g * 4 + r;
      const size_t idx =
          ((size_t)(b_ * Sc + qa)) * Dc + h_ * 64 + dt * 16 + l15;
      const float val = Oacc[dt][r] * linv[r];
      ctx[idx] = val;
      ctxb[idx] = __float2bfloat16(val);
    }
}

// ---------------------------------------------------------------------------
extern "C" void kernel_launch(void* const* d_in, const int* in_sizes, int n_in,
                              void* d_out, int out_size, void* d_ws,
                              size_t ws_size, hipStream_t stream) {
  const float* query = (const float*)d_in[0];
  const float* key_  = (const float*)d_in[1];
  const float* value = (const float*)d_in[2];
  const float* Wq = (const float*)d_in[3];
  const float* bq = (const float*)d_in[4];
  const float* Wk = (const float*)d_in[5];
  const float* bk = (const float*)d_in[6];
  const float* Wv = (const float*)d_in[7];
  const float* bv = (const float*)d_in[8];
  const float* Wd = (const float*)d_in[9];
  const float* bd = (const float*)d_in[10];

  float* out = (float*)d_out;
  float* hidden = out;                 // [B,S,D] fp32 (written LAST)
  float* context = out + OUT_ELEMS;    // [B,S,D] fp32

  // Scratch: Aq/Ak (bf16) live in the hidden region until gemm_qkv is done;
  // hidden is only written by the final gemm_o.
  __hip_bfloat16* Aq = (__hip_bfloat16*)hidden;            // 12.6 MB
  __hip_bfloat16* Ak = Aq + OUT_ELEMS;                     // 12.6 MB

  __hip_bfloat16* Qw  = (__hip_bfloat16*)d_ws;       // [B,H,S,DK]
  __hip_bfloat16* Kw  = Qw + HEAD_ELEMS;             // [B,H,S,DK]
  __hip_bfloat16* Vtw = Kw + HEAD_ELEMS;             // [B,H,DK,S]
  __hip_bfloat16* WtQ = Vtw + HEAD_ELEMS;            // [4][768][768]
  __hip_bfloat16* WtD = WtQ + 3 * (size_t)Dc * Dc;
  __hip_bfloat16* Av  = WtQ + 4 * (size_t)Dc * Dc;   // 12.6 MB
  __hip_bfloat16* ctxb = Av;   // alias: Av dead after gemm_qkv; attn writes it
  // ws total: 37.75 + 4.5 + 12.6 = 54.9 MB  (<= 75.5 MB known-good)

  wtrans4<<<dim3(Dc / 32, Dc / 32, 4), 256, 0, stream>>>(Wq, Wk, Wv, Wd, WtQ);
  cast3<<<dim3(OUT_ELEMS / 8 / 256, 3), 256, 0, stream>>>(
      query, key_, value, Aq, Ak, Av);

  gemm_qkv<<<dim3((BSc / 128) * (Dc / 128), 3), 256, 0, stream>>>(
      Aq, Ak, Av, WtQ, bq, bk, bv, Qw);

  attn_mfma<<<Bc * Hc * (Sc / 64), 256, 0, stream>>>(Qw, Kw, Vtw, context,
                                                     ctxb);

  gemm_o<<<(BSc / 128) * (Dc / 128), 256, 0, stream>>>(ctxb, WtD, bd, hidden);
}